// Round 8
// baseline (560.151 us; speedup 1.0000x reference)
//
#include <hip/hip_runtime.h>
#include <math.h>

#define Dd   512
#define Hh   8
#define Tt   4
#define HDd  64
#define Bb   16
#define Nn   8192
#define HTc  32
#define KS   64
#define NTOK (Bb*Nn)
#define PRUNEc 0.001f
#define EPSc   1e-8f
#define TOKSC 16.0f          // token pre-scale for f16 split (residuals stay normal-range)

// ---- workspace byte offsets (~21 MiB; ws alloc is 1 GiB per fill evidence) ----
#define WS_C1     0u        // 32 f
#define WS_C0     128u      // 32 f
#define WS_CS     2048u     // 32 f  per-ht acc scale = escale/TOKSC
#define WS_FLAG   6144u     // int (mask dtype flag)
#define WS_G2H    65536u    // 32*512 f16 (hi split of row-normalized folded K-proj)
#define WS_G2L    98304u    // 32*512 f16 (lo split)
#define WS_MEAN   163840u   // 131072 f per-token LN mean
#define WS_INV    688128u   // 131072 f per-token LN rsqrt
#define WS_PART   1343488u  // 4096 segs * 32 ht * float2 = 1 MiB (per-wave m,l)
#define WS_PEXP   4194304u  // 16 MiB p[b][ht][n] = exp(s - m_seg)

typedef __attribute__((ext_vector_type(8)))  _Float16 half8v;
typedef __attribute__((ext_vector_type(2)))  __fp16   fp16x2;   // cvt_pkrtz's native type
typedef __attribute__((ext_vector_type(16))) float    f32x16;

// 8 f32 -> 2 f16x8 planes (h = rtz(x), l = rtz(x - h)); all-constant indexing
__device__ __forceinline__ void splitf16x8(float4 v0, float4 v1, half8v &h, half8v &l){
  union { half8v v; fp16x2 p[4]; } H, L;
  H.p[0] = __builtin_amdgcn_cvt_pkrtz(v0.x, v0.y);
  H.p[1] = __builtin_amdgcn_cvt_pkrtz(v0.z, v0.w);
  H.p[2] = __builtin_amdgcn_cvt_pkrtz(v1.x, v1.y);
  H.p[3] = __builtin_amdgcn_cvt_pkrtz(v1.z, v1.w);
  L.p[0] = __builtin_amdgcn_cvt_pkrtz(v0.x - (float)H.p[0][0], v0.y - (float)H.p[0][1]);
  L.p[1] = __builtin_amdgcn_cvt_pkrtz(v0.z - (float)H.p[1][0], v0.w - (float)H.p[1][1]);
  L.p[2] = __builtin_amdgcn_cvt_pkrtz(v1.x - (float)H.p[2][0], v1.y - (float)H.p[2][1]);
  L.p[3] = __builtin_amdgcn_cvt_pkrtz(v1.z - (float)H.p[3][0], v1.w - (float)H.p[3][1]);
  h = H.v; l = L.v;
}

// per-element mask decode given dtype flag (2=f32, 1=u8, 0=i32)
__device__ __forceinline__ int mdecode(const void* mraw, int fl, size_t i){
  if (fl & 2) return ((const float*)mraw)[i] != 0.0f;
  if (fl & 1) return ((const unsigned char*)mraw)[i] != 0;
  return ((const int*)mraw)[i] != 0;
}

__device__ __forceinline__ int chkw(unsigned v){
  return (v == 0x3f800000u) ? 2 : ((v & ~1u) ? 1 : 0);
}

// ---------- fold query path (blocks 0..31) + mask dtype detect (block 32) ----------
// score[n][ht] = inv_n*(x_n . G2eff[ht] - mean_n*C1[ht]) + C0[ht]
// G2eff = escale*(G2h + G2l); stored row-normalized f16 pair; CS = escale/TOKSC.
__global__ void tap_prep(const float* q, const float* ipw, const float* ipb,
                         const float* pre_g, const float* pre_b,
                         const float* q_g, const float* q_b, const float* log_tau,
                         const uint4* mraw, int* flag,
                         _Float16* G2h, _Float16* G2l,
                         float* C1, float* C0, float* CS){
  int tid = threadIdx.x;
  if (blockIdx.x == HTc){              // ---- detect role: bool may arrive i32/u8/f32
    if (tid == 0) *flag = 0;
    __syncthreads();
    int f = 0;
    #pragma unroll
    for (int i = 0; i < 32; ++i){      // 8192 uint4 = first NTOK bytes (safe all layouts)
      uint4 v = mraw[tid + i*256];
      f |= chkw(v.x) | chkw(v.y) | chkw(v.z) | chkw(v.w);
    }
    if (f) atomicOr(flag, f);
    return;
  }
  __shared__ float query[Tt][Dd];
  __shared__ float qps[HDd];
  __shared__ float red[256];
  __shared__ float g2row[Dd];
  __shared__ float escS;
  int ht = blockIdx.x;           // = h*T + t
  int h = ht >> 2, t = ht & 3;
  float tau = expf(log_tau[0]);
  tau = fminf(fmaxf(tau, 0.1f), 10.0f);
  float itau = 1.0f / tau;
  int wv = tid >> 6, lane = tid & 63;
  { // LN of q rows (wave per row)
    const float* qr = q + wv*Dd;
    float s = 0.f, ss = 0.f;
    for (int j = lane; j < Dd; j += 64){ float x = qr[j]; s += x; ss += x*x; }
    #pragma unroll
    for (int off = 32; off; off >>= 1){ s += __shfl_down(s, off); ss += __shfl_down(ss, off); }
    s = __shfl(s, 0); ss = __shfl(ss, 0);
    float mean = s * (1.f/Dd);
    float var  = ss * (1.f/Dd) - mean*mean;
    float inv  = rsqrtf(var + 1e-5f);
    for (int j = lane; j < Dd; j += 64){
      float x = qr[j];
      query[wv][j] = ((x - mean)*inv*q_g[j] + q_b[j]) * itau;
    }
  }
  __syncthreads();
  { // qp[d] = query[t] . wq[h*64+d] + bq   (4 threads per output)
    int d = tid >> 2, sub = tid & 3;
    int i = h*HDd + d;
    const float* wrow = ipw + (size_t)i*Dd;
    float acc = 0.f;
    int j0 = sub*128;
    for (int j = 0; j < 128; ++j) acc += query[t][j0+j]*wrow[j0+j];
    red[tid] = acc;
    __syncthreads();
    if (sub == 0) qps[d] = red[tid]+red[tid+1]+red[tid+2]+red[tid+3] + ipb[i];
    __syncthreads();
  }
  float c0p = 0.f;
  #pragma unroll
  for (int jj = 0; jj < 2; ++jj){
    int j = tid + jj*256;
    float acc = 0.f;
    #pragma unroll 8
    for (int d = 0; d < HDd; ++d)
      acc += qps[d] * ipw[(size_t)(Dd + h*HDd + d)*Dd + j];
    float w2 = acc * 0.125f;          // 1/sqrt(HD)
    g2row[j] = w2 * pre_g[j];
    c0p += w2 * pre_b[j];
  }
  if (tid < HDd) c0p += qps[tid] * ipb[Dd + h*HDd + tid] * 0.125f;  // bk term
  __syncthreads();
  { // row max -> pow2 escale (exact fold-back)
    float mx = fmaxf(fabsf(g2row[tid]), fabsf(g2row[tid + 256]));
    red[tid] = mx; __syncthreads();
    for (int s = 128; s; s >>= 1){ if (tid < s) red[tid] = fmaxf(red[tid], red[tid+s]); __syncthreads(); }
    if (tid == 0){
      float maxv = red[0];
      escS = (maxv > 0.f) ? exp2f(floorf(log2f(maxv))) : 1.f;
      CS[ht] = escS * (1.0f/TOKSC);
    }
    __syncthreads();
  }
  float esc = escS, ie = 1.0f/esc;
  float c1p = 0.f;
  #pragma unroll
  for (int jj = 0; jj < 2; ++jj){
    int j = tid + jj*256;
    float gs = g2row[j] * ie;
    _Float16 hh = (_Float16)gs;
    float r = gs - (float)hh;
    _Float16 ll = (_Float16)r;
    G2h[ht*Dd + j] = hh;
    G2l[ht*Dd + j] = ll;
    // C1 must match the EFFECTIVE g used by the MFMA path: esc*(h+l)
    c1p += esc*((float)hh + (float)ll);
  }
  red[tid] = c1p; __syncthreads();
  for (int s = 128; s; s >>= 1){ if (tid < s) red[tid] += red[tid+s]; __syncthreads(); }
  if (tid == 0) C1[ht] = red[0];
  __syncthreads();
  red[tid] = c0p; __syncthreads();
  for (int s = 128; s; s >>= 1){ if (tid < s) red[tid] += red[tid+s]; __syncthreads(); }
  if (tid == 0) C0[ht] = red[0];
}

// ---------- main: LDS-free streaming f16x2 MFMA scores + online-softmax partials ----------
// Tile: 128 tokens x 32 ht per block (4 waves, one 32x32 MFMA tile each).
// K in 16 steps of 32 elems; BOTH token (HBM) and A (L2) loads are register
// double-buffered and issued at step top, so the per-step wait covers loads
// that had a full step to land (no vmcnt drain of the prefetch).
// f16 2-split (h=rtz, l=rtz residual), all 4 cross-products kept -> error is
// representation-only ~2^-20; tokens pre-scaled x16 and G2 rows normalized by
// pow2 escale (folded back exactly via acc*CS[ht]) keep residuals normal-range.
// NOTE: depth-2 prefetch variant (r7) FAILED the absmax gate — likely VGPR
// overflow under launch_bounds(256,4) -> spill/reorder of LN chains; reverted
// to this verified depth-1 structure. Do not add outer-loop #pragma unroll.
// C/D map (HW-verified): col(token)=lane&31, row(ht)=(r&3)+8*(r>>2)+4*(lane>>5).
__global__ __launch_bounds__(256, 4) void tap_scores(
    const float* __restrict__ tokens,
    const _Float16* __restrict__ G2h, const _Float16* __restrict__ G2l,
    const float* __restrict__ C1, const float* __restrict__ C0,
    const float* __restrict__ CS,
    const void* __restrict__ mraw, const int* __restrict__ flag,
    float* __restrict__ pexp, float2* __restrict__ part,
    float* __restrict__ meanw, float* __restrict__ invw){
  int tid   = threadIdx.x;
  int lane  = tid & 63, wv = tid >> 6;
  int col   = lane & 31;
  int bhalf = lane >> 5;
  size_t t0 = (size_t)blockIdx.x * 128;
  int brow  = (wv << 5) | col;           // this lane's token row in tile
  const float* __restrict__ xrow = tokens + (t0 + brow)*(size_t)Dd;
  int abase = (col << 9) | (bhalf << 3); // A row = ht = col, k-half offset

  f32x16 acc;
  #pragma unroll
  for (int i = 0; i < 16; ++i) acc[i] = 0.f;
  float ps = 0.f, pss = 0.f;

  float4 cT0[2], cT1[2];
  half8v cAh[2], cAl[2];
  #pragma unroll
  for (int sub = 0; sub < 2; ++sub){
    int k0 = (sub << 4) | (bhalf << 3);
    cT0[sub] = *(const float4*)(xrow + k0);
    cT1[sub] = *(const float4*)(xrow + k0 + 4);
    cAh[sub] = *(const half8v*)(G2h + abase + (sub << 4));
    cAl[sub] = *(const half8v*)(G2l + abase + (sub << 4));
  }
  for (int s = 0; s < 16; ++s){
    float4 nT0[2], nT1[2];
    half8v nAh[2], nAl[2];
    int sn = (s + 1) & 15;               // wrap: reloads L1-hot step 0 at the end
    #pragma unroll
    for (int sub = 0; sub < 2; ++sub){
      int k0 = (sn << 5) | (sub << 4) | (bhalf << 3);
      nT0[sub] = *(const float4*)(xrow + k0);
      nT1[sub] = *(const float4*)(xrow + k0 + 4);
      int ga = abase + (sn << 5) + (sub << 4);
      nAh[sub] = *(const half8v*)(G2h + ga);
      nAl[sub] = *(const half8v*)(G2l + ga);
    }
    #pragma unroll
    for (int sub = 0; sub < 2; ++sub){
      float4 v0 = cT0[sub], v1 = cT1[sub];
      ps  += v0.x+v0.y+v0.z+v0.w + v1.x+v1.y+v1.z+v1.w;
      pss += v0.x*v0.x+v0.y*v0.y+v0.z*v0.z+v0.w*v0.w
           + v1.x*v1.x+v1.y*v1.y+v1.z*v1.z+v1.w*v1.w;
      float4 s0 = make_float4(v0.x*TOKSC, v0.y*TOKSC, v0.z*TOKSC, v0.w*TOKSC);
      float4 s1 = make_float4(v1.x*TOKSC, v1.y*TOKSC, v1.z*TOKSC, v1.w*TOKSC);
      half8v bh, bl;
      splitf16x8(s0, s1, bh, bl);
      half8v ah = cAh[sub], al = cAl[sub];
      acc = __builtin_amdgcn_mfma_f32_32x32x16_f16(ah, bh, acc, 0, 0, 0);
      acc = __builtin_amdgcn_mfma_f32_32x32x16_f16(ah, bl, acc, 0, 0, 0);
      acc = __builtin_amdgcn_mfma_f32_32x32x16_f16(al, bh, acc, 0, 0, 0);
      acc = __builtin_amdgcn_mfma_f32_32x32x16_f16(al, bl, acc, 0, 0, 0);
    }
    #pragma unroll
    for (int sub = 0; sub < 2; ++sub){
      cT0[sub] = nT0[sub]; cT1[sub] = nT1[sub];
      cAh[sub] = nAh[sub]; cAl[sub] = nAl[sub];
    }
  }
  // LN stats: merge with k-half sibling (lane ^ 32), then finalize per-lane
  ps  += __shfl_xor(ps, 32);
  pss += __shfl_xor(pss, 32);
  float mean = ps * (1.f/512.f);
  float var  = pss * (1.f/512.f) - mean*mean;
  float inv  = rsqrtf(var + 1e-5f);
  if (bhalf == 0){ meanw[t0 + brow] = mean; invw[t0 + brow] = inv; }
  int fl = *flag;
  int mko = mdecode(mraw, fl, t0 + brow);
  int b = (int)(t0 >> 13);
  int n = (int)(t0 & 8191) + brow;
  int g = (int)blockIdx.x*4 + wv;        // global 32-token segment id
  #pragma unroll
  for (int r = 0; r < 16; ++r){
    int ht = (r & 3) + ((r >> 2) << 3) + (bhalf << 2);
    float sc = mko ? -1e30f : (inv*(acc[r]*CS[ht] - mean*C1[ht]) + C0[ht]);
    float mx = sc;
    #pragma unroll
    for (int off = 16; off; off >>= 1) mx = fmaxf(mx, __shfl_xor(mx, off));
    float p = mko ? 0.f : __expf(sc - mx);
    float ls = p;
    #pragma unroll
    for (int off = 16; off; off >>= 1) ls += __shfl_xor(ls, off);
    pexp[(((size_t)(b*HTc + ht)) << 13) + n] = p;
    if (col == r) part[(size_t)g*HTc + ht] = make_float2(mx, ls);
  }
}

// ---------- fused: (M,L) combine, alpha (8 FMA/token, NO exp), prune, fallback, top-64, pool ----------
// a_n = sum_h p[h][n] * fac[h][seg(n)],  fac = exp(m_seg - M_h)/(8 L_h).
__global__ __launch_bounds__(512, 1) void tap_select(
    const float* __restrict__ tokens, const float* __restrict__ ipw,
    const float* __restrict__ ipb,
    const float* __restrict__ pre_g, const float* __restrict__ pre_b,
    const float* __restrict__ pexp, const float2* __restrict__ part,
    const void* __restrict__ mraw, const int* __restrict__ flag,
    const float* __restrict__ meanw, const float* __restrict__ invw,
    float* __restrict__ out){
  __shared__ float av[Nn];               // 32 KB
  __shared__ float fac[Hh][256];         // 8 KB
  __shared__ float lv[1024];             // 4 KB
  __shared__ int   li[1024];             // 4 KB
  __shared__ float tw[KS]; __shared__ int ti[KS];
  __shared__ float coeff[KS];
  __shared__ __align__(16) float u[Dd];
  __shared__ float rs[8];                       // lsum partials
  __shared__ float rva[8]; __shared__ int ria[8]; __shared__ int rpa[8];
  __shared__ int cnt; __shared__ int sArg; __shared__ float sW, sS;
  int bt = blockIdx.x;
  int b = bt >> 2, t = bt & 3;
  int tid = threadIdx.x, lane = tid & 63, wvi = tid >> 6;
  int fl = *flag;
  if (tid == 0) cnt = 0;
  // ---- per-head global (M,L) from segment partials + fac table: wave h owns head h
  {
    int h = wvi;
    const float2* pb = part + ((size_t)(b << 8))*HTc + (h*Tt + t);
    float2 v0 = pb[(size_t)(lane      )*HTc];
    float2 v1 = pb[(size_t)(lane +  64)*HTc];
    float2 v2 = pb[(size_t)(lane + 128)*HTc];
    float2 v3 = pb[(size_t)(lane + 192)*HTc];
    float M = fmaxf(fmaxf(v0.x, v1.x), fmaxf(v2.x, v3.x));
    #pragma unroll
    for (int off = 32; off; off >>= 1) M = fmaxf(M, __shfl_xor(M, off));
    float L = v0.y*__expf(v0.x - M) + v1.y*__expf(v1.x - M)
            + v2.y*__expf(v2.x - M) + v3.y*__expf(v3.x - M);
    #pragma unroll
    for (int off = 32; off; off >>= 1) L += __shfl_xor(L, off);
    float inv8L = (L > 0.f) ? 0.125f / L : 0.f;
    fac[h][lane      ] = __expf(v0.x - M) * inv8L;
    fac[h][lane +  64] = __expf(v1.x - M) * inv8L;
    fac[h][lane + 128] = __expf(v2.x - M) * inv8L;
    fac[h][lane + 192] = __expf(v3.x - M) * inv8L;
  }
  const float* pr[Hh];
  #pragma unroll
  for (int h = 0; h < Hh; ++h)
    pr[h] = pexp + ((size_t)(b*HTc + h*Tt + t) << 13);
  __syncthreads();
  // ---- a_n, row sum, fallback argmax
  float lsum = 0.f;
  float bvv = -2.f; int bii = 1 << 30;
  #pragma unroll 2
  for (int i = 0; i < 16; ++i){
    int n = tid + (i << 9);
    float a = pr[0][n] * fac[0][n >> 5];
    #pragma unroll
    for (int h = 1; h < Hh; ++h) a += pr[h][n] * fac[h][n >> 5];
    av[n] = a;
    lsum += a;
    float bb = mdecode(mraw, fl, (size_t)b*Nn + n) ? -1.f : a;
    if (bb > bvv || (bb == bvv && n < bii)){ bvv = bb; bii = n; }
  }
  #pragma unroll
  for (int off = 32; off; off >>= 1) lsum += __shfl_down(lsum, off);
  if (lane == 0) rs[wvi] = lsum;
  #pragma unroll
  for (int off = 32; off; off >>= 1){
    float ov = __shfl_down(bvv, off);
    int   oi = __shfl_down(bii, off);
    if (ov > bvv || (ov == bvv && oi < bii)){ bvv = ov; bii = oi; }
  }
  if (lane == 0){ rva[wvi] = bvv; ria[wvi] = bii; }
  __syncthreads();
  float Sall = rs[0]+rs[1]+rs[2]+rs[3]+rs[4]+rs[5]+rs[6]+rs[7];
  if (tid == 0){
    float bv2 = rva[0]; int bi2 = ria[0];
    for (int w2 = 1; w2 < 8; ++w2)
      if (rva[w2] > bv2 || (rva[w2] == bv2 && ria[w2] < bi2)){ bv2 = rva[w2]; bi2 = ria[w2]; }
    sArg = bi2;
  }
  float f1 = 1.0f / fmaxf(Sall, EPSc);
  // ---- compact survivors (normalized value >= PRUNE; at most 1000 since sum<=1)
  #pragma unroll 2
  for (int i = 0; i < 16; ++i){
    int n = tid + (i << 9);
    float x = av[n] * f1;
    if (x >= PRUNEc){
      int id = atomicAdd(&cnt, 1);
      if (id < 1024){ lv[id] = x; li[id] = n; }
    }
  }
  __syncthreads();
  int L = cnt;
  if (L == 0){                           // fallback: onehot at argmax
    if (tid == 0){ lv[0] = 1.f; li[0] = sArg; }
    L = 1;
    __syncthreads();
  }
  if (L <= KS){                          // all survivors selected; zero-fill rest
    if (tid < KS){ tw[tid] = (tid < L) ? lv[tid] : 0.f; ti[tid] = (tid < L) ? li[tid] : 0; }
    __syncthreads();
  } else {
    // exact top-64 (value desc, index asc) over short list (L <= 1000)
    for (int k = 0; k < KS; ++k){
      float bv = -1.f; int bn = 1 << 30; int bp = -1;
      for (int j = tid; j < L; j += 512){
        float x = lv[j]; int nn = li[j];
        if (x > bv || (x == bv && nn < bn)){ bv = x; bn = nn; bp = j; }
      }
      #pragma unroll
      for (int off = 32; off; off >>= 1){
        float ov = __shfl_down(bv, off);
        int   on = __shfl_down(bn, off);
        int   op = __shfl_down(bp, off);
        if (ov > bv || (ov == bv && on < bn)){ bv = ov; bn = on; bp = op; }
      }
      if (lane == 0){ rva[wvi] = bv; ria[wvi] = bn; rpa[wvi] = bp; }
      __syncthreads();
      if (tid == 0){
        float bb = rva[0]; int bj = ria[0]; int pp = rpa[0];
        for (int w2 = 1; w2 < 8; ++w2)
          if (rva[w2] > bb || (rva[w2] == bb && ria[w2] < bj)){ bb = rva[w2]; bj = ria[w2]; pp = rpa[w2]; }
        tw[k] = bb; ti[k] = bj;
        lv[pp] = -1.f;                   // consume
      }
      __syncthreads();
    }
  }
  // ---- pool epilogue (512 threads, one output dim each)
  if (wvi == 0){
    float v = tw[lane];
    #pragma unroll
    for (int off = 32; off; off >>= 1) v += __shfl_down(v, off);
    if (lane == 0) sW = v;
  }
  __syncthreads();
  float sumw = sW;
  float Winv = 1.0f / fmaxf(sumw, EPSc);
  float Wn   = sumw * Winv;
  if (wvi == 0){
    int n = ti[lane];
    float mk2 = meanw[(size_t)b*Nn + n];
    float ik  = invw [(size_t)b*Nn + n];
    float wn  = tw[lane] * Winv;
    coeff[lane] = wn * ik;
    float sp = wn * mk2 * ik;
    #pragma unroll
    for (int off = 32; off; off >>= 1) sp += __shfl_down(sp, off);
    if (lane == 0) sS = sp;
  }
  __syncthreads();
  float Sv = sS;
  int d = tid;
  float acc0 = 0.f;
  #pragma unroll 4
  for (int k = 0; k < KS; ++k){          // branchless: c==0 rows contribute 0
    float c = coeff[k];
    acc0 = fmaf(c, tokens[((size_t)b*Nn + ti[k])*Dd + d], acc0);
  }
  u[d] = pre_g[d]*(acc0 - Sv) + pre_b[d]*Wn;
  __syncthreads();
  const float4* u4 = (const float4*)u;
  const float4* w0 = (const float4*)(ipw + (size_t)(2*Dd + d)*Dd);
  float o0 = 0.f;
  #pragma unroll 4
  for (int j4 = 0; j4 < 128; ++j4){
    float4 uu = u4[j4];
    float4 a = w0[j4];
    o0 += uu.x*a.x + uu.y*a.y + uu.z*a.z + uu.w*a.w;
  }
  out[bt*Dd + d] = o0 + Wn*ipb[2*Dd + d];
}

extern "C" void kernel_launch(void* const* d_in, const int* in_sizes, int n_in,
                              void* d_out, int out_size, void* d_ws, size_t ws_size,
                              hipStream_t stream){
  const float* tokens = (const float*)d_in[0];
  const void*  kpm    = d_in[1];
  const float* q      = (const float*)d_in[2];
  const float* ipw    = (const float*)d_in[3];
  const float* ipb    = (const float*)d_in[4];
  const float* pre_g  = (const float*)d_in[5];
  const float* pre_b  = (const float*)d_in[6];
  const float* q_g    = (const float*)d_in[7];
  const float* q_b    = (const float*)d_in[8];
  const float* ltau   = (const float*)d_in[9];
  char* ws = (char*)d_ws;
  float* C1    = (float*)(ws + WS_C1);
  float* C0    = (float*)(ws + WS_C0);
  float* CSs   = (float*)(ws + WS_CS);
  int*   flag  = (int*)  (ws + WS_FLAG);
  _Float16* G2h = (_Float16*)(ws + WS_G2H);
  _Float16* G2l = (_Float16*)(ws + WS_G2L);
  float* meanw = (float*)(ws + WS_MEAN);
  float* invw  = (float*)(ws + WS_INV);
  float2* part = (float2*)(ws + WS_PART);
  float* pexp  = (float*)(ws + WS_PEXP);
  float* out = (float*)d_out;

  hipLaunchKernelGGL(tap_prep,   dim3(HTc + 1), dim3(256), 0, stream,
                     q, ipw, ipb, pre_g, pre_b, q_g, q_b, ltau,
                     (const uint4*)kpm, flag, G2h, G2l, C1, C0, CSs);
  hipLaunchKernelGGL(tap_scores, dim3(NTOK/128), dim3(256), 0, stream,
                     tokens, G2h, G2l, C1, C0, CSs, kpm, flag, pexp, part, meanw, invw);
  hipLaunchKernelGGL(tap_select, dim3(Bb*Tt), dim3(512), 0, stream,
                     tokens, ipw, ipb, pre_g, pre_b, pexp, part, kpm, flag,
                     meanw, invw, out);
}